// Round 6
// baseline (1263.226 us; speedup 1.0000x reference)
//
#include <hip/hip_runtime.h>
#include <hip/hip_bf16.h>

// ---------------------------------------------------------------------------
// RecurrentBattleNet: 2-layer LSTM (B=512, T=256, IN=512, H=128) + FC head.
// Round 6: fix weight-fragment rematerialization in the recurrence —
// __launch_bounds__(512,2) raises the VGPR cap to 256 and an empty
// asm volatile pin keeps the 64-VGPR Whh fragment set live across steps
// (R4/R5 had VGPR_Count 80/92 < the ~136 required -> per-step reloads on
// the MFMA critical path were the ~4100 idle cyc/step).
// ---------------------------------------------------------------------------

#define BATCH 512
#define SEQT  256
#define INPUTD 512
#define HID   128
#define GATES 512   // 4*HID
#define RB    16    // batch rows per recurrence block

typedef __bf16 bf16_t;
typedef bf16_t bf16x4 __attribute__((ext_vector_type(4)));
typedef bf16_t bf16x8 __attribute__((ext_vector_type(8)));
typedef float  f32x4  __attribute__((ext_vector_type(4)));

__device__ __forceinline__ float sigm(float x) {
    return 1.f / (1.f + __expf(-x));
}
__device__ __forceinline__ float tanhfast(float x) {
    float xc = fminf(fmaxf(x, -15.f), 15.f);
    float e = __expf(2.f * xc);
    return (e - 1.f) / (e + 1.f);
}

// ---------------------------------------------------------------------------
// fp32 -> bf16 conversion, vectorized (float4 in, bf16x4 out). n4 = n/4.
// ---------------------------------------------------------------------------
__global__ __launch_bounds__(256) void cvt_f32_bf16(
    const float* __restrict__ in, bf16_t* __restrict__ out, long n4)
{
    long i = (long)blockIdx.x * 256 + threadIdx.x;
    long stride = (long)gridDim.x * 256;
    for (; i < n4; i += stride) {
        float4 v = ((const float4*)in)[i];
        bf16x4 r;
        r[0] = (bf16_t)v.x; r[1] = (bf16_t)v.y;
        r[2] = (bf16_t)v.z; r[3] = (bf16_t)v.w;
        ((bf16x4*)out)[i] = r;
    }
}

// ---------------------------------------------------------------------------
// bf16 MFMA GEMM: out[m][n] = sum_k A(m)[k]*W[n][k] + b1[n] + b2[n], n<512.
// Logical A-row m -> physical row (m>>tcs)*srcT + t0 + (m&tcmask), stride K.
// 128x128 tile, BK=32, 256 thr (4 waves 2x2), 16x16x32 MFMA, 4x4 tiles/wave.
// ---------------------------------------------------------------------------
__global__ __launch_bounds__(256) void gemm_mfma(
    const bf16_t* __restrict__ A, const bf16_t* __restrict__ W,
    const float* __restrict__ b1, const float* __restrict__ b2,
    float* __restrict__ out,
    int K, int tcs, int tcmask, int srcT, int t0)
{
    __shared__ bf16_t As[128 * 32];
    __shared__ bf16_t Bs[128 * 32];
    int tid = threadIdx.x;
    int l = tid & 63;
    int w = tid >> 6;
    int wm = w >> 1, wn = w & 1;
    int bn = blockIdx.x;
    int bm = blockIdx.y;

    long aoff[2], boff[2];
    #pragma unroll
    for (int c = 0; c < 2; ++c) {
        int m = bm * 128 + (tid >> 2) + 64 * c;
        int xr = ((m >> tcs) * srcT) + t0 + (m & tcmask);
        aoff[c] = (long)xr * K + (tid & 3) * 8;
        int n = bn * 128 + (tid >> 2) + 64 * c;
        boff[c] = (long)n * K + (tid & 3) * 8;
    }

    f32x4 acc[4][4];
    #pragma unroll
    for (int i = 0; i < 4; ++i)
        #pragma unroll
        for (int j = 0; j < 4; ++j)
            acc[i][j] = (f32x4){0.f, 0.f, 0.f, 0.f};

    const int rbase = wm * 64 + (l & 15);
    const int cbase = wn * 64 + (l & 15);
    const int kfrag = (l >> 4) * 8;

    for (int kt = 0; kt < K; kt += 32) {
        __builtin_amdgcn_global_load_lds(
            (const __attribute__((address_space(1))) void*)(A + aoff[0] + kt),
            (__attribute__((address_space(3))) void*)(As + tid * 8), 16, 0, 0);
        __builtin_amdgcn_global_load_lds(
            (const __attribute__((address_space(1))) void*)(A + aoff[1] + kt),
            (__attribute__((address_space(3))) void*)(As + 2048 + tid * 8), 16, 0, 0);
        __builtin_amdgcn_global_load_lds(
            (const __attribute__((address_space(1))) void*)(W + boff[0] + kt),
            (__attribute__((address_space(3))) void*)(Bs + tid * 8), 16, 0, 0);
        __builtin_amdgcn_global_load_lds(
            (const __attribute__((address_space(1))) void*)(W + boff[1] + kt),
            (__attribute__((address_space(3))) void*)(Bs + 2048 + tid * 8), 16, 0, 0);
        __syncthreads();

        bf16x8 af[4], bfr[4];
        #pragma unroll
        for (int i = 0; i < 4; ++i)
            af[i] = *(const bf16x8*)(As + (rbase + i * 16) * 32 + kfrag);
        #pragma unroll
        for (int j = 0; j < 4; ++j)
            bfr[j] = *(const bf16x8*)(Bs + (cbase + j * 16) * 32 + kfrag);

        #pragma unroll
        for (int i = 0; i < 4; ++i)
            #pragma unroll
            for (int j = 0; j < 4; ++j)
                acc[i][j] = __builtin_amdgcn_mfma_f32_16x16x32_bf16(
                    af[i], bfr[j], acc[i][j], 0, 0, 0);
        __syncthreads();
    }

    #pragma unroll
    for (int i = 0; i < 4; ++i) {
        int m = bm * 128 + wm * 64 + i * 16 + (l >> 4) * 4;
        #pragma unroll
        for (int j = 0; j < 4; ++j) {
            int n = bn * 128 + wn * 64 + j * 16 + (l & 15);
            float bb = b1[n] + b2[n];
            #pragma unroll
            for (int r = 0; r < 4; ++r)
                out[(long)(m + r) * GATES + n] = acc[i][j][r] + bb;
        }
    }
}

// ---------------------------------------------------------------------------
// MFMA LSTM recurrence. Block owns RB=16 batch rows for all Tc steps.
// 8 waves; wave w owns gate cols {g*128 + w*16 .. +16} for g=i,f,g,o ->
// each lane's 4 acc tiles hold i,f,g,o for the same (row, hid-elem):
// c-update is register-local. h double-buffered in swizzled LDS (bf16).
// Whh fragments pinned in VGPRs (64/lane, asm-pinned vs remat).
// Raw s_barrier per step (lgkmcnt(0) only) so xp prefetch / hseq stores
// stay in flight across the barrier.
// ---------------------------------------------------------------------------
#define REC_STEP_BODY(XN, RD, WR)                                              \
    {                                                                          \
        f32x4 acc[4];                                                          \
        _Pragma("unroll")                                                      \
        for (int g = 0; g < 4; ++g) {                                          \
            acc[g][0] = XN[g][0]; acc[g][1] = XN[g][1];                        \
            acc[g][2] = XN[g][2]; acc[g][3] = XN[g][3];                        \
        }                                                                      \
        if (t + 2 < Tc) {                                                      \
            _Pragma("unroll")                                                  \
            for (int g = 0; g < 4; ++g)                                        \
                _Pragma("unroll")                                              \
                for (int r = 0; r < 4; ++r)                                    \
                    XN[g][r] = xp[((long)(r0 + rowg + r) * Tc + t + 2) * GATES \
                                  + g * 128 + coff];                           \
        }                                                                      \
        const char* hb = (const char*)h_lds[RD];                               \
        _Pragma("unroll")                                                      \
        for (int ks = 0; ks < 4; ++ks) {                                       \
            int ba = (col * 256 + ks * 64 + (l >> 4) * 16) ^ ((col & 7) << 4); \
            bf16x8 a = *(const bf16x8*)(hb + ba);                              \
            _Pragma("unroll")                                                  \
            for (int g = 0; g < 4; ++g)                                        \
                acc[g] = __builtin_amdgcn_mfma_f32_16x16x32_bf16(              \
                    a, __builtin_bit_cast(bf16x8, wreg[g][ks]), acc[g],        \
                    0, 0, 0);                                                  \
        }                                                                      \
        char* hw = (char*)h_lds[WR];                                           \
        _Pragma("unroll")                                                      \
        for (int r = 0; r < 4; ++r) {                                          \
            float gi = acc[0][r], gf = acc[1][r];                              \
            float gg = acc[2][r], go = acc[3][r];                              \
            c[r] = sigm(gf) * c[r] + sigm(gi) * tanhfast(gg);                  \
            hv[r] = sigm(go) * tanhfast(c[r]);                                 \
            int row = rowg + r;                                                \
            int ba = (row * 256 + coff * 2) ^ ((row & 7) << 4);                \
            *(bf16_t*)(hw + ba) = (bf16_t)hv[r];                               \
            if (hseq)                                                          \
                hseq[((long)(r0 + row) * Tc + t) * HID + coff] =               \
                    (bf16_t)hv[r];                                             \
        }                                                                      \
        asm volatile("s_waitcnt lgkmcnt(0)" ::: "memory");                     \
        __builtin_amdgcn_s_barrier();                                          \
        asm volatile("" ::: "memory");                                         \
    }

__global__ __launch_bounds__(512, 2) void lstm_rec_mfma(
    const float* __restrict__ xp,    // [B, Tc, 512]
    const bf16_t* __restrict__ Whh,  // [512,128] bf16
    bf16_t* __restrict__ hseq,       // [B, Tc, 128] bf16 or nullptr
    float* __restrict__ hst, float* __restrict__ cst,  // [B,128]
    int Tc, int first)
{
    __shared__ __align__(16) bf16_t h_lds[2][RB * HID];  // swizzled
    int tid = threadIdx.x;
    int l = tid & 63;
    int w = tid >> 6;                 // wave 0..7
    int r0 = blockIdx.x * RB;

    int col = l & 15;                 // within-tile col
    int coff = w * 16 + col;          // owned hid-elem (0..127)
    int rowg = (l >> 4) * 4;          // batch-row group base (C/D layout)
    int kreg = (l >> 4) * 8;          // A/B fragment k offset

    // persistent weight fragments, loaded once and PINNED in VGPRs:
    // wreg[g][ks] = Whh[g*128+coff][ks*32+kreg ..+8] (16B each)
    f32x4 wreg[4][4];
    #pragma unroll
    for (int g = 0; g < 4; ++g)
        #pragma unroll
        for (int ks = 0; ks < 4; ++ks)
            wreg[g][ks] = *(const f32x4*)(Whh + (g * 128 + coff) * HID + ks * 32 + kreg);
    // sever the load->use chain so LLVM cannot rematerialize the loads
    // inside the step loop (R4/R5: VGPR_Count 80/92 proved it did).
    #pragma unroll
    for (int g = 0; g < 4; ++g)
        #pragma unroll
        for (int ks = 0; ks < 4; ++ks)
            asm volatile("" : "+v"(wreg[g][ks]));

    f32x4 c;
    #pragma unroll
    for (int r = 0; r < 4; ++r)
        c[r] = first ? 0.f : cst[(r0 + rowg + r) * HID + coff];

    // stage h_init into h_lds[0] (swizzled): 512 thr x 4 elems
    {
        int idx = tid * 4;
        int row = idx >> 7;
        int k = idx & 127;
        float4 hv4 = make_float4(0.f, 0.f, 0.f, 0.f);
        if (!first) hv4 = *(const float4*)(hst + (r0 + row) * HID + k);
        bf16x4 hb4;
        hb4[0] = (bf16_t)hv4.x; hb4[1] = (bf16_t)hv4.y;
        hb4[2] = (bf16_t)hv4.z; hb4[3] = (bf16_t)hv4.w;
        int ba = (row * 256 + k * 2) ^ ((row & 7) << 4);
        *(bf16x4*)((char*)h_lds[0] + ba) = hb4;
    }
    __syncthreads();

    // depth-2 prefetch: xnA holds step t, xnB holds step t+1 (named sets,
    // compile-time indexed)
    float xnA[4][4], xnB[4][4];
    #pragma unroll
    for (int g = 0; g < 4; ++g)
        #pragma unroll
        for (int r = 0; r < 4; ++r) {
            xnA[g][r] = xp[((long)(r0 + rowg + r) * Tc + 0) * GATES + g * 128 + coff];
            xnB[g][r] = (Tc > 1)
                ? xp[((long)(r0 + rowg + r) * Tc + 1) * GATES + g * 128 + coff]
                : 0.f;
        }

    float hv[4] = {0.f, 0.f, 0.f, 0.f};

    for (int tt = 0; tt < Tc; tt += 2) {
        {
            int t = tt;
            REC_STEP_BODY(xnA, 0, 1)
        }
        {
            int t = tt + 1;
            REC_STEP_BODY(xnB, 1, 0)
        }
    }

    #pragma unroll
    for (int r = 0; r < 4; ++r) {
        hst[(r0 + rowg + r) * HID + coff] = hv[r];
        cst[(r0 + rowg + r) * HID + coff] = c[r];
    }
}

// ---------------------------------------------------------------------------
// FC head + softmax + state copy-out. One block per batch row, 128 threads.
// out layout: probs [512*10] | h_n [2*512*128] | c_n [2*512*128]
// ---------------------------------------------------------------------------
__global__ __launch_bounds__(128) void fc_head(
    const float* __restrict__ h0st, const float* __restrict__ c0st,
    const float* __restrict__ h1st, const float* __restrict__ c1st,
    const float* __restrict__ fc1w, const float* __restrict__ fc1b,
    const float* __restrict__ fc2w, const float* __restrict__ fc2b,
    float* __restrict__ out)
{
    __shared__ float h1_s[HID];
    __shared__ float hid_s[64];
    __shared__ float log_s[10];
    int t = threadIdx.x;
    int b = blockIdx.x;

    h1_s[t] = h1st[b * HID + t];
    __syncthreads();

    if (t < 64) {
        float a = fc1b[t];
        const float* wrow = fc1w + t * HID;
        #pragma unroll 4
        for (int k = 0; k < HID; ++k) a = fmaf(wrow[k], h1_s[k], a);
        hid_s[t] = fmaxf(a, 0.f);
    }
    __syncthreads();

    if (t < 10) {
        float a = fc2b[t];
        const float* wrow = fc2w + t * 64;
        #pragma unroll 4
        for (int k = 0; k < 64; ++k) a = fmaf(wrow[k], hid_s[k], a);
        log_s[t] = a;
    }
    __syncthreads();

    if (t == 0) {
        float m = log_s[0];
        #pragma unroll
        for (int j = 1; j < 10; ++j) m = fmaxf(m, log_s[j]);
        float e[10];
        float s = 0.f;
        #pragma unroll
        for (int j = 0; j < 10; ++j) { e[j] = __expf(log_s[j] - m); s += e[j]; }
        float inv = 1.f / s;
        #pragma unroll
        for (int j = 0; j < 10; ++j) out[b * 10 + j] = e[j] * inv;
    }

    float* hn = out + BATCH * 10;
    float* cn = hn + 2 * BATCH * HID;
    hn[b * HID + t] = h0st[b * HID + t];
    hn[BATCH * HID + b * HID + t] = h1_s[t];
    cn[b * HID + t] = c0st[b * HID + t];
    cn[BATCH * HID + b * HID + t] = c1st[b * HID + t];
}

// ---------------------------------------------------------------------------
extern "C" void kernel_launch(void* const* d_in, const int* in_sizes, int n_in,
                              void* d_out, int out_size, void* d_ws, size_t ws_size,
                              hipStream_t stream) {
    const float* x    = (const float*)d_in[0];
    const float* Wih0 = (const float*)d_in[1];
    const float* Whh0 = (const float*)d_in[2];
    const float* bih0 = (const float*)d_in[3];
    const float* bhh0 = (const float*)d_in[4];
    const float* Wih1 = (const float*)d_in[5];
    const float* Whh1 = (const float*)d_in[6];
    const float* bih1 = (const float*)d_in[7];
    const float* bhh1 = (const float*)d_in[8];
    const float* fc1w = (const float*)d_in[9];
    const float* fc1b = (const float*)d_in[10];
    const float* fc2w = (const float*)d_in[11];
    const float* fc2b = (const float*)d_in[12];
    float* out = (float*)d_out;

    int Tc = SEQT;
    while (Tc > 1) {
        size_t need = (size_t)BATCH * Tc * GATES * 4       // xp
                    + (size_t)BATCH * Tc * HID * 2         // h0b
                    + (size_t)BATCH * SEQT * INPUTD * 2    // xb
                    + ((size_t)GATES * INPUTD + 3 * (size_t)GATES * HID) * 2
                    + 4 * (size_t)BATCH * HID * 4 + 256;
        if (need <= ws_size) break;
        Tc >>= 1;
    }
    int tcs = __builtin_ctz((unsigned)Tc);

    float*  xp   = (float*)d_ws;
    bf16_t* h0b  = (bf16_t*)(xp + (size_t)BATCH * Tc * GATES);
    bf16_t* xb   = h0b + (size_t)BATCH * Tc * HID;
    bf16_t* wb0  = xb + (size_t)BATCH * SEQT * INPUTD;
    bf16_t* wb1  = wb0 + (size_t)GATES * INPUTD;
    bf16_t* wh0b = wb1 + (size_t)GATES * HID;
    bf16_t* wh1b = wh0b + (size_t)GATES * HID;
    float*  h0st = (float*)(wh1b + (size_t)GATES * HID);
    float*  c0st = h0st + (size_t)BATCH * HID;
    float*  h1st = c0st + (size_t)BATCH * HID;
    float*  c1st = h1st + (size_t)BATCH * HID;

    cvt_f32_bf16<<<2048, 256, 0, stream>>>(x, xb, (long)BATCH * SEQT * INPUTD / 4);
    cvt_f32_bf16<<<256, 256, 0, stream>>>(Wih0, wb0, (long)GATES * INPUTD / 4);
    cvt_f32_bf16<<<64, 256, 0, stream>>>(Wih1, wb1, (long)GATES * HID / 4);
    cvt_f32_bf16<<<64, 256, 0, stream>>>(Whh0, wh0b, (long)GATES * HID / 4);
    cvt_f32_bf16<<<64, 256, 0, stream>>>(Whh1, wh1b, (long)GATES * HID / 4);

    int nchunk = SEQT / Tc;
    dim3 gemm_grid(GATES / 128, (BATCH * Tc) / 128);

    for (int ci = 0; ci < nchunk; ++ci) {
        int t0 = ci * Tc;
        gemm_mfma<<<gemm_grid, 256, 0, stream>>>(
            xb, wb0, bih0, bhh0, xp, INPUTD, tcs, Tc - 1, SEQT, t0);
        lstm_rec_mfma<<<BATCH / RB, 512, 0, stream>>>(
            xp, wh0b, h0b, h0st, c0st, Tc, ci == 0);
        gemm_mfma<<<gemm_grid, 256, 0, stream>>>(
            h0b, wb1, bih1, bhh1, xp, HID, tcs, Tc - 1, Tc, 0);
        lstm_rec_mfma<<<BATCH / RB, 512, 0, stream>>>(
            xp, wh1b, nullptr, h1st, c1st, Tc, ci == 0);
    }

    fc_head<<<BATCH, 128, 0, stream>>>(
        h0st, c0st, h1st, c1st, fc1w, fc1b, fc2w, fc2b, out);
}

// Round 7
// 949.568 us; speedup vs baseline: 1.3303x; 1.3303x over previous
//
#include <hip/hip_runtime.h>
#include <hip/hip_bf16.h>

// ---------------------------------------------------------------------------
// RecurrentBattleNet: 2-layer LSTM (B=512, T=256, IN=512, H=128) + FC head.
// Round 7: recurrence is VALU-ISSUE-bound on its 32 active CUs (device-avg
// VALUBusy 9% x 256/32 = ~72% active). Cut per-step VALU: blocked xp layout
// (GEMM writes rec-thread-order, rec loads 16 coalesced dwords w/ trivial
// addressing), hseq written via post-barrier LDS readback (1 ds_read_b64 +
// 1 8B store vs 16 scalar 2B stores), v_rcp_f32 for all sig/tanh divides.
// ---------------------------------------------------------------------------

#define BATCH 512
#define SEQT  256
#define INPUTD 512
#define HID   128
#define GATES 512   // 4*HID
#define RB    16    // batch rows per recurrence block

typedef __bf16 bf16_t;
typedef bf16_t bf16x4 __attribute__((ext_vector_type(4)));
typedef bf16_t bf16x8 __attribute__((ext_vector_type(8)));
typedef float  f32x4  __attribute__((ext_vector_type(4)));

__device__ __forceinline__ float sigm(float x) {
    return __builtin_amdgcn_rcpf(1.f + __expf(-x));
}
__device__ __forceinline__ float tanhfast(float x) {
    float xc = fminf(fmaxf(x, -15.f), 15.f);
    float e = __expf(2.f * xc);
    return (e - 1.f) * __builtin_amdgcn_rcpf(e + 1.f);
}

// ---------------------------------------------------------------------------
// fp32 -> bf16 conversion, vectorized (float4 in, bf16x4 out). n4 = n/4.
// ---------------------------------------------------------------------------
__global__ __launch_bounds__(256) void cvt_f32_bf16(
    const float* __restrict__ in, bf16_t* __restrict__ out, long n4)
{
    long i = (long)blockIdx.x * 256 + threadIdx.x;
    long stride = (long)gridDim.x * 256;
    for (; i < n4; i += stride) {
        float4 v = ((const float4*)in)[i];
        bf16x4 r;
        r[0] = (bf16_t)v.x; r[1] = (bf16_t)v.y;
        r[2] = (bf16_t)v.z; r[3] = (bf16_t)v.w;
        ((bf16x4*)out)[i] = r;
    }
}

// ---------------------------------------------------------------------------
// bf16 MFMA GEMM, writing the BLOCKED xp layout consumed by lstm_rec_mfma:
//   xp2[br][t][idx(16)][tid(512)]  (floats)
// where for gate-col n and batch row b: br=b>>4, brow=b&15,
//   tid = ((n>>4)&7)*64 + (brow>>2)*16 + (n&15),  idx = (n>>7)*4 + (brow&3).
// A-side: logical row m -> physical row (m>>tcs)*srcT + t0 + (m&tcmask).
// ---------------------------------------------------------------------------
__global__ __launch_bounds__(256) void gemm_mfma(
    const bf16_t* __restrict__ A, const bf16_t* __restrict__ W,
    const float* __restrict__ b1, const float* __restrict__ b2,
    float* __restrict__ out,
    int K, int tcs, int tcmask, int srcT, int t0)
{
    __shared__ bf16_t As[128 * 32];
    __shared__ bf16_t Bs[128 * 32];
    int tid = threadIdx.x;
    int l = tid & 63;
    int w = tid >> 6;
    int wm = w >> 1, wn = w & 1;
    int bn = blockIdx.x;
    int bm = blockIdx.y;
    int Tc = tcmask + 1;

    long aoff[2], boff[2];
    #pragma unroll
    for (int c = 0; c < 2; ++c) {
        int m = bm * 128 + (tid >> 2) + 64 * c;
        int xr = ((m >> tcs) * srcT) + t0 + (m & tcmask);
        aoff[c] = (long)xr * K + (tid & 3) * 8;
        int n = bn * 128 + (tid >> 2) + 64 * c;
        boff[c] = (long)n * K + (tid & 3) * 8;
    }

    f32x4 acc[4][4];
    #pragma unroll
    for (int i = 0; i < 4; ++i)
        #pragma unroll
        for (int j = 0; j < 4; ++j)
            acc[i][j] = (f32x4){0.f, 0.f, 0.f, 0.f};

    const int rbase = wm * 64 + (l & 15);
    const int cbase = wn * 64 + (l & 15);
    const int kfrag = (l >> 4) * 8;

    for (int kt = 0; kt < K; kt += 32) {
        __builtin_amdgcn_global_load_lds(
            (const __attribute__((address_space(1))) void*)(A + aoff[0] + kt),
            (__attribute__((address_space(3))) void*)(As + tid * 8), 16, 0, 0);
        __builtin_amdgcn_global_load_lds(
            (const __attribute__((address_space(1))) void*)(A + aoff[1] + kt),
            (__attribute__((address_space(3))) void*)(As + 2048 + tid * 8), 16, 0, 0);
        __builtin_amdgcn_global_load_lds(
            (const __attribute__((address_space(1))) void*)(W + boff[0] + kt),
            (__attribute__((address_space(3))) void*)(Bs + tid * 8), 16, 0, 0);
        __builtin_amdgcn_global_load_lds(
            (const __attribute__((address_space(1))) void*)(W + boff[1] + kt),
            (__attribute__((address_space(3))) void*)(Bs + 2048 + tid * 8), 16, 0, 0);
        __syncthreads();

        bf16x8 af[4], bfr[4];
        #pragma unroll
        for (int i = 0; i < 4; ++i)
            af[i] = *(const bf16x8*)(As + (rbase + i * 16) * 32 + kfrag);
        #pragma unroll
        for (int j = 0; j < 4; ++j)
            bfr[j] = *(const bf16x8*)(Bs + (cbase + j * 16) * 32 + kfrag);

        #pragma unroll
        for (int i = 0; i < 4; ++i)
            #pragma unroll
            for (int j = 0; j < 4; ++j)
                acc[i][j] = __builtin_amdgcn_mfma_f32_16x16x32_bf16(
                    af[i], bfr[j], acc[i][j], 0, 0, 0);
        __syncthreads();
    }

    // epilogue: write blocked xp2 layout (C row = (l>>4)*4 + r, col = l&15)
    #pragma unroll
    for (int i = 0; i < 4; ++i) {
        int m0 = bm * 128 + wm * 64 + i * 16 + (l >> 4) * 4;
        #pragma unroll
        for (int j = 0; j < 4; ++j) {
            int n = bn * 128 + wn * 64 + j * 16 + (l & 15);
            float bb = b1[n] + b2[n];
            int g = n >> 7;
            int wg = (n >> 4) & 7;
            int colg = n & 15;
            #pragma unroll
            for (int r = 0; r < 4; ++r) {
                int m = m0 + r;
                int b = m >> tcs;
                int t = m & tcmask;
                int br = b >> 4, brow = b & 15;
                int tr = wg * 64 + (brow >> 2) * 16 + colg;
                int idx = g * 4 + (brow & 3);
                out[(((long)br * Tc + t) * 16 + idx) * 512 + tr] =
                    acc[i][j][r] + bb;
            }
        }
    }
}

// ---------------------------------------------------------------------------
// MFMA LSTM recurrence. Block owns RB=16 batch rows for all Tc steps.
// 8 waves; wave w owns gate cols {g*128 + w*16 .. +16} for g=i,f,g,o ->
// lane's 4 acc tiles hold i,f,g,o for the same (row, hid-elem): c-update
// register-local. h double-buffered in swizzled LDS (bf16). Whh persistent
// in VGPRs. xp2 blocked layout: lane reads 16 dwords at stride 2KB.
// hseq written post-barrier from LDS (8B/thread coalesced).
// ---------------------------------------------------------------------------
#define REC_STEP_BODY(XN, RD, WR)                                              \
    {                                                                          \
        f32x4 acc[4];                                                          \
        _Pragma("unroll")                                                      \
        for (int g = 0; g < 4; ++g)                                            \
            _Pragma("unroll")                                                  \
            for (int r = 0; r < 4; ++r)                                        \
                acc[g][r] = XN[g * 4 + r];                                     \
        if (t + 2 < Tc) {                                                      \
            _Pragma("unroll")                                                  \
            for (int k = 0; k < 16; ++k)                                       \
                XN[k] = xpb[((long)(t + 2) * 16 + k) * 512];                   \
        }                                                                      \
        const char* hb = (const char*)h_lds[RD];                               \
        _Pragma("unroll")                                                      \
        for (int ks = 0; ks < 4; ++ks) {                                       \
            int ba = (col * 256 + ks * 64 + lgroup * 16) ^ ((col & 7) << 4);   \
            bf16x8 a = *(const bf16x8*)(hb + ba);                              \
            _Pragma("unroll")                                                  \
            for (int g = 0; g < 4; ++g)                                        \
                acc[g] = __builtin_amdgcn_mfma_f32_16x16x32_bf16(              \
                    a, __builtin_bit_cast(bf16x8, wreg[g][ks]), acc[g],        \
                    0, 0, 0);                                                  \
        }                                                                      \
        char* hw = (char*)h_lds[WR];                                           \
        _Pragma("unroll")                                                      \
        for (int r = 0; r < 4; ++r) {                                          \
            float gi = acc[0][r], gf = acc[1][r];                              \
            float gg = acc[2][r], go = acc[3][r];                              \
            c[r] = sigm(gf) * c[r] + sigm(gi) * tanhfast(gg);                  \
            hv[r] = sigm(go) * tanhfast(c[r]);                                 \
            int row = rowg + r;                                                \
            int ba = (row * 256 + coff * 2) ^ ((row & 7) << 4);                \
            *(bf16_t*)(hw + ba) = (bf16_t)hv[r];                               \
        }                                                                      \
        asm volatile("s_waitcnt lgkmcnt(0)" ::: "memory");                     \
        __builtin_amdgcn_s_barrier();                                          \
        asm volatile("" ::: "memory");                                         \
        if (hseq) {                                                            \
            bf16x4 h4v = *(const bf16x4*)((const char*)h_lds[WR] + hba);       \
            *(bf16x4*)(hqp + (long)t * HID) = h4v;                             \
        }                                                                      \
    }

__global__ __launch_bounds__(512, 2) void lstm_rec_mfma(
    const float* __restrict__ xp2,   // [B/16][Tc][16][512] blocked
    const bf16_t* __restrict__ Whh,  // [512,128] bf16
    bf16_t* __restrict__ hseq,       // [B, Tc, 128] bf16 or nullptr
    float* __restrict__ hst, float* __restrict__ cst,  // [B,128]
    int Tc, int first)
{
    __shared__ __align__(16) bf16_t h_lds[2][RB * HID];  // swizzled
    int tid = threadIdx.x;
    int l = tid & 63;
    int w = tid >> 6;                 // wave 0..7
    int r0 = blockIdx.x * RB;

    int col = l & 15;                 // within-tile col
    int lgroup = l >> 4;              // 0..3
    int coff = w * 16 + col;          // owned hid-elem (0..127)
    int rowg = lgroup * 4;            // batch-row group base (C/D layout)
    int kreg = lgroup * 8;            // A/B fragment k offset

    // per-lane xp2 base: element (t*16 + idx)*512 + tid within block region
    const float* xpb = xp2 + (long)blockIdx.x * Tc * 16 * 512 + tid;

    // hseq writeback mapping: thread -> 4 consecutive bf16 of row (tid>>5)
    int hrow = tid >> 5, hk = (tid & 31) * 4;
    const int hba = (hrow * 256 + hk * 2) ^ ((hrow & 7) << 4);
    bf16_t* hqp = hseq ? hseq + ((long)(r0 + hrow) * Tc) * HID + hk : nullptr;

    // persistent weight fragments (64 VGPR/lane)
    f32x4 wreg[4][4];
    #pragma unroll
    for (int g = 0; g < 4; ++g)
        #pragma unroll
        for (int ks = 0; ks < 4; ++ks)
            wreg[g][ks] = *(const f32x4*)(Whh + (g * 128 + coff) * HID + ks * 32 + kreg);
    #pragma unroll
    for (int g = 0; g < 4; ++g)
        #pragma unroll
        for (int ks = 0; ks < 4; ++ks)
            asm volatile("" : "+v"(wreg[g][ks]));

    f32x4 c;
    #pragma unroll
    for (int r = 0; r < 4; ++r)
        c[r] = first ? 0.f : cst[(r0 + rowg + r) * HID + coff];

    // stage h_init into h_lds[0] (swizzled): 512 thr x 4 elems
    {
        int idx = tid * 4;
        int row = idx >> 7;
        int k = idx & 127;
        float4 hv4 = make_float4(0.f, 0.f, 0.f, 0.f);
        if (!first) hv4 = *(const float4*)(hst + (r0 + row) * HID + k);
        bf16x4 hb4;
        hb4[0] = (bf16_t)hv4.x; hb4[1] = (bf16_t)hv4.y;
        hb4[2] = (bf16_t)hv4.z; hb4[3] = (bf16_t)hv4.w;
        int ba = (row * 256 + k * 2) ^ ((row & 7) << 4);
        *(bf16x4*)((char*)h_lds[0] + ba) = hb4;
    }
    __syncthreads();

    // depth-2 prefetch, named sets (compile-time indexed)
    float xnA[16], xnB[16];
    #pragma unroll
    for (int k = 0; k < 16; ++k) {
        xnA[k] = xpb[(long)k * 512];
        xnB[k] = (Tc > 1) ? xpb[(long)(16 + k) * 512] : 0.f;
    }

    float hv[4] = {0.f, 0.f, 0.f, 0.f};

    for (int tt = 0; tt < Tc; tt += 2) {
        {
            int t = tt;
            REC_STEP_BODY(xnA, 0, 1)
        }
        {
            int t = tt + 1;
            REC_STEP_BODY(xnB, 1, 0)
        }
    }

    #pragma unroll
    for (int r = 0; r < 4; ++r) {
        hst[(r0 + rowg + r) * HID + coff] = hv[r];
        cst[(r0 + rowg + r) * HID + coff] = c[r];
    }
}

// ---------------------------------------------------------------------------
// FC head + softmax + state copy-out. One block per batch row, 128 threads.
// out layout: probs [512*10] | h_n [2*512*128] | c_n [2*512*128]
// ---------------------------------------------------------------------------
__global__ __launch_bounds__(128) void fc_head(
    const float* __restrict__ h0st, const float* __restrict__ c0st,
    const float* __restrict__ h1st, const float* __restrict__ c1st,
    const float* __restrict__ fc1w, const float* __restrict__ fc1b,
    const float* __restrict__ fc2w, const float* __restrict__ fc2b,
    float* __restrict__ out)
{
    __shared__ float h1_s[HID];
    __shared__ float hid_s[64];
    __shared__ float log_s[10];
    int t = threadIdx.x;
    int b = blockIdx.x;

    h1_s[t] = h1st[b * HID + t];
    __syncthreads();

    if (t < 64) {
        float a = fc1b[t];
        const float* wrow = fc1w + t * HID;
        #pragma unroll 4
        for (int k = 0; k < HID; ++k) a = fmaf(wrow[k], h1_s[k], a);
        hid_s[t] = fmaxf(a, 0.f);
    }
    __syncthreads();

    if (t < 10) {
        float a = fc2b[t];
        const float* wrow = fc2w + t * 64;
        #pragma unroll 4
        for (int k = 0; k < 64; ++k) a = fmaf(wrow[k], hid_s[k], a);
        log_s[t] = a;
    }
    __syncthreads();

    if (t == 0) {
        float m = log_s[0];
        #pragma unroll
        for (int j = 1; j < 10; ++j) m = fmaxf(m, log_s[j]);
        float e[10];
        float s = 0.f;
        #pragma unroll
        for (int j = 0; j < 10; ++j) { e[j] = __expf(log_s[j] - m); s += e[j]; }
        float inv = __builtin_amdgcn_rcpf(s);
        #pragma unroll
        for (int j = 0; j < 10; ++j) out[b * 10 + j] = e[j] * inv;
    }

    float* hn = out + BATCH * 10;
    float* cn = hn + 2 * BATCH * HID;
    hn[b * HID + t] = h0st[b * HID + t];
    hn[BATCH * HID + b * HID + t] = h1_s[t];
    cn[b * HID + t] = c0st[b * HID + t];
    cn[BATCH * HID + b * HID + t] = c1st[b * HID + t];
}

// ---------------------------------------------------------------------------
extern "C" void kernel_launch(void* const* d_in, const int* in_sizes, int n_in,
                              void* d_out, int out_size, void* d_ws, size_t ws_size,
                              hipStream_t stream) {
    const float* x    = (const float*)d_in[0];
    const float* Wih0 = (const float*)d_in[1];
    const float* Whh0 = (const float*)d_in[2];
    const float* bih0 = (const float*)d_in[3];
    const float* bhh0 = (const float*)d_in[4];
    const float* Wih1 = (const float*)d_in[5];
    const float* Whh1 = (const float*)d_in[6];
    const float* bih1 = (const float*)d_in[7];
    const float* bhh1 = (const float*)d_in[8];
    const float* fc1w = (const float*)d_in[9];
    const float* fc1b = (const float*)d_in[10];
    const float* fc2w = (const float*)d_in[11];
    const float* fc2b = (const float*)d_in[12];
    float* out = (float*)d_out;

    int Tc = SEQT;
    while (Tc > 1) {
        size_t need = (size_t)BATCH * Tc * GATES * 4       // xp2
                    + (size_t)BATCH * Tc * HID * 2         // h0b
                    + (size_t)BATCH * SEQT * INPUTD * 2    // xb
                    + ((size_t)GATES * INPUTD + 3 * (size_t)GATES * HID) * 2
                    + 4 * (size_t)BATCH * HID * 4 + 256;
        if (need <= ws_size) break;
        Tc >>= 1;
    }
    int tcs = __builtin_ctz((unsigned)Tc);

    float*  xp   = (float*)d_ws;
    bf16_t* h0b  = (bf16_t*)(xp + (size_t)BATCH * Tc * GATES);
    bf16_t* xb   = h0b + (size_t)BATCH * Tc * HID;
    bf16_t* wb0  = xb + (size_t)BATCH * SEQT * INPUTD;
    bf16_t* wb1  = wb0 + (size_t)GATES * INPUTD;
    bf16_t* wh0b = wb1 + (size_t)GATES * HID;
    bf16_t* wh1b = wh0b + (size_t)GATES * HID;
    float*  h0st = (float*)(wh1b + (size_t)GATES * HID);
    float*  c0st = h0st + (size_t)BATCH * HID;
    float*  h1st = c0st + (size_t)BATCH * HID;
    float*  c1st = h1st + (size_t)BATCH * HID;

    cvt_f32_bf16<<<2048, 256, 0, stream>>>(x, xb, (long)BATCH * SEQT * INPUTD / 4);
    cvt_f32_bf16<<<256, 256, 0, stream>>>(Wih0, wb0, (long)GATES * INPUTD / 4);
    cvt_f32_bf16<<<64, 256, 0, stream>>>(Wih1, wb1, (long)GATES * HID / 4);
    cvt_f32_bf16<<<64, 256, 0, stream>>>(Whh0, wh0b, (long)GATES * HID / 4);
    cvt_f32_bf16<<<64, 256, 0, stream>>>(Whh1, wh1b, (long)GATES * HID / 4);

    int nchunk = SEQT / Tc;
    dim3 gemm_grid(GATES / 128, (BATCH * Tc) / 128);

    for (int ci = 0; ci < nchunk; ++ci) {
        int t0 = ci * Tc;
        gemm_mfma<<<gemm_grid, 256, 0, stream>>>(
            xb, wb0, bih0, bhh0, xp, INPUTD, tcs, Tc - 1, SEQT, t0);
        lstm_rec_mfma<<<BATCH / RB, 512, 0, stream>>>(
            xp, wh0b, h0b, h0st, c0st, Tc, ci == 0);
        gemm_mfma<<<gemm_grid, 256, 0, stream>>>(
            h0b, wb1, bih1, bhh1, xp, HID, tcs, Tc - 1, Tc, 0);
        lstm_rec_mfma<<<BATCH / RB, 512, 0, stream>>>(
            xp, wh1b, nullptr, h1st, c1st, Tc, ci == 0);
    }

    fc_head<<<BATCH, 128, 0, stream>>>(
        h0st, c0st, h1st, c1st, fc1w, fc1b, fc2w, fc2b, out);
}